// Round 11
// baseline (366.261 us; speedup 1.0000x reference)
//
#include <hip/hip_runtime.h>
#include <math.h>

// ---------------------------------------------------------------------------
// ResGatedGraphConv x2 + global_mean_pool + FC.
// R2: bf16 MFMA GEMMs. R4: rcp/exp2 sigmoid. R8: QV interleave, no pool
//     atomics. R9: direct-slot CSR, gemm1 stages fp32 X, S bf16.
// R10: scatter fused into gemm1 dispatch (independent work overlaps);
//      edge_agg processes 2 edges per slot-iteration (8 gathers in flight
//      per wave), pair loop + tail, all loads loop-local (no spill).
//      7 dispatches: prep, gemm1+scatter, edge1, gemm2, edge2, pool, fc.
// ---------------------------------------------------------------------------

typedef __attribute__((ext_vector_type(8))) short short8;
typedef __attribute__((ext_vector_type(4))) float floatx4;
typedef __attribute__((ext_vector_type(8))) unsigned short ushort8v;

#define LOG2E 1.4426950408889634f
#define DSTRIDE 96   // CSR row slots; deg ~ Binom(800k,1/50k): mean16 sd4

__device__ __forceinline__ unsigned short f2b(float f) {
  unsigned int u = __builtin_bit_cast(unsigned int, f);
  u += 0x7fff + ((u >> 16) & 1);   // RNE
  return (unsigned short)(u >> 16);
}
__device__ __forceinline__ float blo(unsigned int u) {
  return __builtin_bit_cast(float, u << 16);
}
__device__ __forceinline__ float bhi(unsigned int u) {
  return __builtin_bit_cast(float, u & 0xffff0000u);
}

// ------- fused prep: zero cnt | pack W bf16 [n][k] | pack biases ----

__global__ __launch_bounds__(256) void prep_kernel(
    const float* __restrict__ Wk1, const float* __restrict__ Wq1,
    const float* __restrict__ Wv1, const float* __restrict__ Ws1,
    const float* __restrict__ Wk2, const float* __restrict__ Wq2,
    const float* __restrict__ Wv2, const float* __restrict__ Ws2,
    unsigned short* __restrict__ WT,
    const float* __restrict__ bk1, const float* __restrict__ bq1,
    const float* __restrict__ bv1, const float* __restrict__ bs1,
    const float* __restrict__ b1,
    const float* __restrict__ bk2, const float* __restrict__ bq2,
    const float* __restrict__ bv2, const float* __restrict__ bs2,
    const float* __restrict__ b2,
    float* __restrict__ bcat,
    int* __restrict__ cnt, int ncnt4, int nzerob) {
  int b = blockIdx.x;
  if (b < nzerob) {
    int i = b * 256 + threadIdx.x;
    if (i < ncnt4) ((int4*)cnt)[i] = make_int4(0, 0, 0, 0);
    return;
  }
  b -= nzerob;
  if (b < 512) {
    int idx = b * 256 + threadIdx.x;   // 0 .. 131071
    int layer = idx >> 16;
    int rem = idx & 0xFFFF;
    int mat = rem >> 14;
    int nk = rem & 0x3FFF;
    int nn = nk >> 7, kk = nk & 127;
    int sel = layer * 4 + mat;
    const float* W = (sel == 0) ? Wk1 : (sel == 1) ? Wq1 : (sel == 2) ? Wv1 :
                     (sel == 3) ? Ws1 : (sel == 4) ? Wk2 : (sel == 5) ? Wq2 :
                     (sel == 6) ? Wv2 : Ws2;
    WT[idx] = f2b(W[kk * 128 + nn]);
    return;
  }
  b -= 512;
  {
    int idx = b * 256 + threadIdx.x;   // 0 .. 1023
    if (idx >= 1024) return;
    int layer = idx >> 9;
    int rem = idx & 511;
    int mat = rem >> 7, c = rem & 127;
    int sel = layer * 4 + mat;
    const float* bb = (sel == 0) ? bk1 : (sel == 1) ? bq1 : (sel == 2) ? bv1 :
                      (sel == 3) ? bs1 : (sel == 4) ? bk2 : (sel == 5) ? bq2 :
                      (sel == 6) ? bv2 : bs2;
    float v = bb[c];
    if (mat == 3) v += (layer == 0) ? b1[c] : b2[c];
    bcat[idx] = v;
  }
}

// --- MFMA GEMM (+ optional fused edge scatter in trailing blocks) ---
// gemm blocks: b < gemmBlocks, x-tile = b>>1, mat-pair = b&1.
// scatter blocks: direct-slot CSR es[dst*96 + atomicAdd(cnt[dst])] = src.
// Input: fp32 Xf (layer 1) or bf16 Xb (layer 2). Outputs bf16:
// m0 -> Kb[n][128]; m1 -> QV[n][0..127]; m2 -> QV[n][128..255]; m3 -> Sb.

__global__ __launch_bounds__(256) void gemm_mfma_kernel(
    const float* __restrict__ Xf, const unsigned short* __restrict__ Xb,
    int use_fp32,
    const unsigned short* __restrict__ WT,   // [4][128 n][128 k] bf16
    const float* __restrict__ bcat,          // [4][128]
    unsigned short* __restrict__ Kb, unsigned short* __restrict__ QV,
    unsigned short* __restrict__ Sb, int n, int gemmBlocks,
    const int* __restrict__ esrc, const int* __restrict__ edst,
    int* __restrict__ cnt, int* __restrict__ es, int E) {
  __shared__ unsigned short aT[128 * 136];     // 34.8 KB
  __shared__ float estage_all[4][16 * 68];     // 17.4 KB, per-wave strips

  int t = threadIdx.x;

  if (blockIdx.x >= gemmBlocks) {   // ---- fused scatter ----
    int e = (blockIdx.x - gemmBlocks) * 256 + t;
    if (e < E) {
      int i = edst[e];
      int p = atomicAdd(&cnt[i], 1);
      if (p < DSTRIDE) es[i * DSTRIDE + p] = esrc[e];
    }
    return;
  }

  int row0 = (blockIdx.x >> 1) * 128;
  int ysel = blockIdx.x & 1;

  if (use_fp32) {
#pragma unroll
    for (int i = 0; i < 8; ++i) {
      int c = i * 256 + t;          // 8-ch chunk id, 0..2047
      int r = c >> 4, col16 = c & 15;
      ushort8v o;
#pragma unroll
      for (int q = 0; q < 8; ++q) o[q] = 0;
      if (row0 + r < n) {
        float4 u0 = *(const float4*)&Xf[(size_t)(row0 + r) * 128 + col16 * 8];
        float4 u1 = *(const float4*)&Xf[(size_t)(row0 + r) * 128 + col16 * 8 + 4];
        o[0] = f2b(u0.x); o[1] = f2b(u0.y); o[2] = f2b(u0.z); o[3] = f2b(u0.w);
        o[4] = f2b(u1.x); o[5] = f2b(u1.y); o[6] = f2b(u1.z); o[7] = f2b(u1.w);
      }
      *(ushort8v*)&aT[r * 136 + col16 * 8] = o;
    }
  } else {
#pragma unroll
    for (int i = 0; i < 8; ++i) {
      int c = i * 256 + t;
      int r = c >> 4, col16 = c & 15;
      int4 v = make_int4(0, 0, 0, 0);
      if (row0 + r < n) v = *(const int4*)&Xb[(size_t)(row0 + r) * 128 + col16 * 8];
      *(int4*)&aT[r * 136 + col16 * 8] = v;
    }
  }
  __syncthreads();

  int lane = t & 63, wid = t >> 6;
  int wy = wid >> 1, wx = wid & 1;
  int l15 = lane & 15, lq = lane >> 4;
  int r4 = lane >> 2, cq4 = lane & 3;
  int col = wx * 64 + cq4 * 16;
  float* estage = estage_all[wid];

#pragma unroll
  for (int mm = 0; mm < 2; ++mm) {
    int m = ysel * 2 + mm;
    const unsigned short* WTm = WT + (size_t)m * 16384;

    floatx4 acc[4][4];
#pragma unroll
    for (int mf = 0; mf < 4; ++mf)
#pragma unroll
      for (int nf = 0; nf < 4; ++nf) acc[mf][nf] = (floatx4)(0.0f);

#pragma unroll
    for (int ks = 0; ks < 4; ++ks) {
      int kof = ks * 32 + lq * 8;
      short8 a[4], b[4];
#pragma unroll
      for (int mf = 0; mf < 4; ++mf)
        a[mf] = *(const short8*)&aT[(wy * 64 + mf * 16 + l15) * 136 + kof];
#pragma unroll
      for (int nf = 0; nf < 4; ++nf)
        b[nf] = *(const short8*)&WTm[(size_t)(wx * 64 + nf * 16 + l15) * 128 + kof];
#pragma unroll
      for (int mf = 0; mf < 4; ++mf)
#pragma unroll
        for (int nf = 0; nf < 4; ++nf)
          acc[mf][nf] = __builtin_amdgcn_mfma_f32_16x16x32_bf16(a[mf], b[nf], acc[mf][nf], 0, 0, 0);
    }

    const float* bias = bcat + m * 128;
    float4 bv[4];
#pragma unroll
    for (int j = 0; j < 4; ++j) bv[j] = *(const float4*)&bias[col + j * 4];

    unsigned short* Ob;
    int ostr;
    if (m == 0)      { Ob = Kb;       ostr = 128; }
    else if (m == 1) { Ob = QV;       ostr = 256; }
    else if (m == 2) { Ob = QV + 128; ostr = 256; }
    else             { Ob = Sb;       ostr = 128; }

#pragma unroll
    for (int mf = 0; mf < 4; ++mf) {
#pragma unroll
      for (int nf = 0; nf < 4; ++nf)
#pragma unroll
        for (int i = 0; i < 4; ++i)
          estage[(lq * 4 + i) * 68 + nf * 16 + l15] = acc[mf][nf][i];
      // per-wave region, wave-lockstep: no barrier needed
      int grow = row0 + wy * 64 + mf * 16 + r4;
      if (grow < n) {
        float4 p[4];
#pragma unroll
        for (int j = 0; j < 4; ++j) {
          float4 e = *(const float4*)&estage[r4 * 68 + cq4 * 16 + j * 4];
          p[j].x = e.x + bv[j].x; p[j].y = e.y + bv[j].y;
          p[j].z = e.z + bv[j].z; p[j].w = e.w + bv[j].w;
        }
        ushort8v o0, o1;
        o0[0] = f2b(p[0].x); o0[1] = f2b(p[0].y); o0[2] = f2b(p[0].z); o0[3] = f2b(p[0].w);
        o0[4] = f2b(p[1].x); o0[5] = f2b(p[1].y); o0[6] = f2b(p[1].z); o0[7] = f2b(p[1].w);
        o1[0] = f2b(p[2].x); o1[1] = f2b(p[2].y); o1[2] = f2b(p[2].z); o1[3] = f2b(p[2].w);
        o1[4] = f2b(p[3].x); o1[5] = f2b(p[3].y); o1[6] = f2b(p[3].z); o1[7] = f2b(p[3].w);
        *(ushort8v*)&Ob[(size_t)grow * ostr + col] = o0;
        *(ushort8v*)&Ob[(size_t)grow * ostr + col + 8] = o1;
      }
    }
  }
}

// ---------------- edge aggregation + residual + relu ----------------
// h[i] = relu( S[i] + sum_j sigmoid(K[i]+Q[j]) * V[j] )
// One node per wave; 4 edge slots x 16 lanes x 8 ch; TWO edges per slot
// iteration (e, e+4 -> 8 gathers in flight per wave); all loads loop-local.

__global__ __launch_bounds__(256) void edge_agg_kernel(
    const unsigned short* __restrict__ Kb, const unsigned short* __restrict__ QV,
    const unsigned short* __restrict__ Sb, const int* __restrict__ cnt,
    const int* __restrict__ es, unsigned short* __restrict__ Hb, int n) {
  int wid = threadIdx.x >> 6;
  int lane = threadIdx.x & 63;
  int node = blockIdx.x * 4 + wid;
  if (node >= n) return;
  int slot = lane >> 4;      // edge slot 0..3
  int l16 = lane & 15;       // channels l16*8 .. l16*8+7
  int chb = l16 * 8;

  uint4 kk = *(const uint4*)&Kb[(size_t)node * 128 + chb];
  float kc0 = blo(kk.x) * (-LOG2E), kc1 = bhi(kk.x) * (-LOG2E);
  float kc2 = blo(kk.y) * (-LOG2E), kc3 = bhi(kk.y) * (-LOG2E);
  float kc4 = blo(kk.z) * (-LOG2E), kc5 = bhi(kk.z) * (-LOG2E);
  float kc6 = blo(kk.w) * (-LOG2E), kc7 = bhi(kk.w) * (-LOG2E);

  float a0 = 0.f, a1 = 0.f, a2 = 0.f, a3 = 0.f;
  float a4 = 0.f, a5 = 0.f, a6 = 0.f, a7 = 0.f;

  int count = cnt[node];
  if (count > DSTRIDE) count = DSTRIDE;
  const int* row = es + (size_t)node * DSTRIDE;
  int e = slot;
  // pair loop: edges e and e+4 (both guaranteed in range)
  while (e + 4 < count) {
    int j0 = row[e];
    int j1 = row[e + 4];
    const unsigned short* qv0 = &QV[(size_t)j0 * 256 + chb];
    const unsigned short* qv1 = &QV[(size_t)j1 * 256 + chb];
    uint4 q8 = *(const uint4*)qv0;
    uint4 v8 = *(const uint4*)(qv0 + 128);
    uint4 q9 = *(const uint4*)qv1;
    uint4 v9 = *(const uint4*)(qv1 + 128);
    float ex;
    ex = __builtin_amdgcn_exp2f(fmaf(blo(q8.x), -LOG2E, kc0));
    a0 = fmaf(blo(v8.x), __builtin_amdgcn_rcpf(1.0f + ex), a0);
    ex = __builtin_amdgcn_exp2f(fmaf(bhi(q8.x), -LOG2E, kc1));
    a1 = fmaf(bhi(v8.x), __builtin_amdgcn_rcpf(1.0f + ex), a1);
    ex = __builtin_amdgcn_exp2f(fmaf(blo(q8.y), -LOG2E, kc2));
    a2 = fmaf(blo(v8.y), __builtin_amdgcn_rcpf(1.0f + ex), a2);
    ex = __builtin_amdgcn_exp2f(fmaf(bhi(q8.y), -LOG2E, kc3));
    a3 = fmaf(bhi(v8.y), __builtin_amdgcn_rcpf(1.0f + ex), a3);
    ex = __builtin_amdgcn_exp2f(fmaf(blo(q8.z), -LOG2E, kc4));
    a4 = fmaf(blo(v8.z), __builtin_amdgcn_rcpf(1.0f + ex), a4);
    ex = __builtin_amdgcn_exp2f(fmaf(bhi(q8.z), -LOG2E, kc5));
    a5 = fmaf(bhi(v8.z), __builtin_amdgcn_rcpf(1.0f + ex), a5);
    ex = __builtin_amdgcn_exp2f(fmaf(blo(q8.w), -LOG2E, kc6));
    a6 = fmaf(blo(v8.w), __builtin_amdgcn_rcpf(1.0f + ex), a6);
    ex = __builtin_amdgcn_exp2f(fmaf(bhi(q8.w), -LOG2E, kc7));
    a7 = fmaf(bhi(v8.w), __builtin_amdgcn_rcpf(1.0f + ex), a7);
    ex = __builtin_amdgcn_exp2f(fmaf(blo(q9.x), -LOG2E, kc0));
    a0 = fmaf(blo(v9.x), __builtin_amdgcn_rcpf(1.0f + ex), a0);
    ex = __builtin_amdgcn_exp2f(fmaf(bhi(q9.x), -LOG2E, kc1));
    a1 = fmaf(bhi(v9.x), __builtin_amdgcn_rcpf(1.0f + ex), a1);
    ex = __builtin_amdgcn_exp2f(fmaf(blo(q9.y), -LOG2E, kc2));
    a2 = fmaf(blo(v9.y), __builtin_amdgcn_rcpf(1.0f + ex), a2);
    ex = __builtin_amdgcn_exp2f(fmaf(bhi(q9.y), -LOG2E, kc3));
    a3 = fmaf(bhi(v9.y), __builtin_amdgcn_rcpf(1.0f + ex), a3);
    ex = __builtin_amdgcn_exp2f(fmaf(blo(q9.z), -LOG2E, kc4));
    a4 = fmaf(blo(v9.z), __builtin_amdgcn_rcpf(1.0f + ex), a4);
    ex = __builtin_amdgcn_exp2f(fmaf(bhi(q9.z), -LOG2E, kc5));
    a5 = fmaf(bhi(v9.z), __builtin_amdgcn_rcpf(1.0f + ex), a5);
    ex = __builtin_amdgcn_exp2f(fmaf(blo(q9.w), -LOG2E, kc6));
    a6 = fmaf(blo(v9.w), __builtin_amdgcn_rcpf(1.0f + ex), a6);
    ex = __builtin_amdgcn_exp2f(fmaf(bhi(q9.w), -LOG2E, kc7));
    a7 = fmaf(bhi(v9.w), __builtin_amdgcn_rcpf(1.0f + ex), a7);
    e += 8;
  }
  if (e < count) {
    int j0 = row[e];
    const unsigned short* qv0 = &QV[(size_t)j0 * 256 + chb];
    uint4 q8 = *(const uint4*)qv0;
    uint4 v8 = *(const uint4*)(qv0 + 128);
    float ex;
    ex = __builtin_amdgcn_exp2f(fmaf(blo(q8.x), -LOG2E, kc0));
    a0 = fmaf(blo(v8.x), __builtin_amdgcn_rcpf(1.0f + ex), a0);
    ex = __builtin_amdgcn_exp2f(fmaf(bhi(q8.x), -LOG2E, kc1));
    a1 = fmaf(bhi(v8.x), __builtin_amdgcn_rcpf(1.0f + ex), a1);
    ex = __builtin_amdgcn_exp2f(fmaf(blo(q8.y), -LOG2E, kc2));
    a2 = fmaf(blo(v8.y), __builtin_amdgcn_rcpf(1.0f + ex), a2);
    ex = __builtin_amdgcn_exp2f(fmaf(bhi(q8.y), -LOG2E, kc3));
    a3 = fmaf(bhi(v8.y), __builtin_amdgcn_rcpf(1.0f + ex), a3);
    ex = __builtin_amdgcn_exp2f(fmaf(blo(q8.z), -LOG2E, kc4));
    a4 = fmaf(blo(v8.z), __builtin_amdgcn_rcpf(1.0f + ex), a4);
    ex = __builtin_amdgcn_exp2f(fmaf(bhi(q8.z), -LOG2E, kc5));
    a5 = fmaf(bhi(v8.z), __builtin_amdgcn_rcpf(1.0f + ex), a5);
    ex = __builtin_amdgcn_exp2f(fmaf(blo(q8.w), -LOG2E, kc6));
    a6 = fmaf(blo(v8.w), __builtin_amdgcn_rcpf(1.0f + ex), a6);
    ex = __builtin_amdgcn_exp2f(fmaf(bhi(q8.w), -LOG2E, kc7));
    a7 = fmaf(bhi(v8.w), __builtin_amdgcn_rcpf(1.0f + ex), a7);
  }

  // combine 4 edge slots
  a0 += __shfl_xor(a0, 16); a0 += __shfl_xor(a0, 32);
  a1 += __shfl_xor(a1, 16); a1 += __shfl_xor(a1, 32);
  a2 += __shfl_xor(a2, 16); a2 += __shfl_xor(a2, 32);
  a3 += __shfl_xor(a3, 16); a3 += __shfl_xor(a3, 32);
  a4 += __shfl_xor(a4, 16); a4 += __shfl_xor(a4, 32);
  a5 += __shfl_xor(a5, 16); a5 += __shfl_xor(a5, 32);
  a6 += __shfl_xor(a6, 16); a6 += __shfl_xor(a6, 32);
  a7 += __shfl_xor(a7, 16); a7 += __shfl_xor(a7, 32);

  if (slot == 0) {
    uint4 sb = *(const uint4*)&Sb[(size_t)node * 128 + chb];
    float r0 = fmaxf(a0 + blo(sb.x), 0.f), r1 = fmaxf(a1 + bhi(sb.x), 0.f);
    float r2 = fmaxf(a2 + blo(sb.y), 0.f), r3 = fmaxf(a3 + bhi(sb.y), 0.f);
    float r4 = fmaxf(a4 + blo(sb.z), 0.f), r5 = fmaxf(a5 + bhi(sb.z), 0.f);
    float r6 = fmaxf(a6 + blo(sb.w), 0.f), r7 = fmaxf(a7 + bhi(sb.w), 0.f);
    ushort8v o;
    o[0] = f2b(r0); o[1] = f2b(r1); o[2] = f2b(r2); o[3] = f2b(r3);
    o[4] = f2b(r4); o[5] = f2b(r5); o[6] = f2b(r6); o[7] = f2b(r7);
    *(ushort8v*)&Hb[(size_t)node * 128 + chb] = o;
  }
}

// ---------------- mean pool + FC (graph bounds via binary search) ----------

__device__ __forceinline__ int lb_batch(const int* __restrict__ batch, int n, int key) {
  int lo = 0, hi = n;
  while (lo < hi) {
    int mid = (lo + hi) >> 1;
    if (batch[mid] < key) lo = mid + 1; else hi = mid;
  }
  return lo;
}

// 16 slices per graph -> partial[slice][g][128], no atomics.
__global__ __launch_bounds__(256) void pool_sum_kernel(const unsigned short* __restrict__ Hb,
                                                       const int* __restrict__ batch,
                                                       float* __restrict__ partial, int n) {
  __shared__ float red[8 * 128];
  int g = blockIdx.x >> 4;
  int slice = blockIdx.x & 15;
  int t = threadIdx.x;
  int grp = t >> 5;        // 0..7: node stripe
  int cq = t & 31;         // channel quad: ch cq*4..cq*4+3
  int s = lb_batch(batch, n, g), e = lb_batch(batch, n, g + 1);
  int cntn = e - s;
  int per = (cntn + 15) >> 4;
  int ss = s + slice * per;
  int ee = ss + per; if (ee > e) ee = e;

  float4 acc = make_float4(0.f, 0.f, 0.f, 0.f);
  for (int nd = ss + grp; nd < ee; nd += 8) {
    uint2 u = *(const uint2*)&Hb[(size_t)nd * 128 + cq * 4];
    acc.x += blo(u.x); acc.y += bhi(u.x);
    acc.z += blo(u.y); acc.w += bhi(u.y);
  }
  *(float4*)&red[grp * 128 + cq * 4] = acc;
  __syncthreads();
  if (t < 128) {
    float tot = 0.f;
#pragma unroll
    for (int g8 = 0; g8 < 8; ++g8) tot += red[g8 * 128 + t];
    partial[(size_t)slice * 8192 + g * 128 + t] = tot;
  }
}

__global__ __launch_bounds__(128) void fc_kernel(const float* __restrict__ partial,
                                                 const int* __restrict__ batch,
                                                 const float* __restrict__ fcW,
                                                 const float* __restrict__ fcb,
                                                 float* __restrict__ out, int n) {
  __shared__ float p[128];
  int g = blockIdx.x;
  int t = threadIdx.x;
  int cntn = lb_batch(batch, n, g + 1) - lb_batch(batch, n, g);
  float inv = 1.0f / (float)((cntn > 0) ? cntn : 1);
  float tot = 0.f;
#pragma unroll
  for (int s = 0; s < 16; ++s) tot += partial[(size_t)s * 8192 + g * 128 + t];
  p[t] = tot * inv;
  __syncthreads();
  if (t < 10) {
    float s = fcb[t];
    for (int c = 0; c < 128; ++c) s += p[c] * fcW[c * 10 + t];
    out[g * 10 + t] = s;
  }
}

// ---------------------------------------------------------------------------

extern "C" void kernel_launch(void* const* d_in, const int* in_sizes, int n_in,
                              void* d_out, int out_size, void* d_ws, size_t ws_size,
                              hipStream_t stream) {
  const float* x   = (const float*)d_in[0];
  const int* eidx  = (const int*)d_in[1];
  const int* batch = (const int*)d_in[2];
  const float* Wk1 = (const float*)d_in[3];  const float* bk1 = (const float*)d_in[4];
  const float* Wq1 = (const float*)d_in[5];  const float* bq1 = (const float*)d_in[6];
  const float* Wv1 = (const float*)d_in[7];  const float* bv1 = (const float*)d_in[8];
  const float* Ws1 = (const float*)d_in[9];  const float* bs1 = (const float*)d_in[10];
  const float* b1  = (const float*)d_in[11];
  const float* Wk2 = (const float*)d_in[12]; const float* bk2 = (const float*)d_in[13];
  const float* Wq2 = (const float*)d_in[14]; const float* bq2 = (const float*)d_in[15];
  const float* Wv2 = (const float*)d_in[16]; const float* bv2 = (const float*)d_in[17];
  const float* Ws2 = (const float*)d_in[18]; const float* bs2 = (const float*)d_in[19];
  const float* b2  = (const float*)d_in[20];
  const float* fcW = (const float*)d_in[21]; const float* fcb = (const float*)d_in[22];
  float* out = (float*)d_out;

  const int N = in_sizes[0] / 128;   // 50000
  const int E = in_sizes[1] / 2;     // 800000
  const int* src = eidx;
  const int* dst = eidx + E;

  // ---- workspace carve ----
  char* w = (char*)d_ws;
  size_t off = 0;
  auto carve = [&](size_t bytes) -> void* {
    void* p = w + off;
    off += (bytes + 255) & ~size_t(255);
    return p;
  };
  const size_t featB16 = (size_t)N * 128 * 2;
  unsigned short* Kb = (unsigned short*)carve(featB16);
  unsigned short* QV = (unsigned short*)carve(featB16 * 2);  // [n][256] Q|V
  unsigned short* Hb = (unsigned short*)carve(featB16);
  unsigned short* Sb = (unsigned short*)carve(featB16);
  unsigned short* WT = (unsigned short*)carve(2 * 4 * 128 * 128 * 2);
  float* bcat = (float*)carve(1024 * 4);
  int* cnt     = (int*)carve(((size_t)N + 4) * 4);
  int* es      = (int*)carve((size_t)N * DSTRIDE * 4);
  float* partial = (float*)carve((size_t)16 * 64 * 128 * 4);
  (void)ws_size; (void)n_in; (void)out_size;

  // ---- prep (zero cnt, pack weights/biases) ----
  int ncnt4 = (N + 3) / 4;
  int nzerob = (ncnt4 + 255) / 256;
  prep_kernel<<<nzerob + 512 + 4, 256, 0, stream>>>(
      Wk1, Wq1, Wv1, Ws1, Wk2, Wq2, Wv2, Ws2, WT,
      bk1, bq1, bv1, bs1, b1, bk2, bq2, bv2, bs2, b2, bcat,
      cnt, ncnt4, nzerob);

  int gemmBlocks = ((N + 127) / 128) * 2;
  int scatterBlocks = (E + 255) / 256;

  // ---- layer 1: gemm (fp32 x staged directly) + fused CSR scatter ----
  gemm_mfma_kernel<<<gemmBlocks + scatterBlocks, 256, 0, stream>>>(
      x, nullptr, 1, WT, bcat, Kb, QV, Sb, N, gemmBlocks,
      src, dst, cnt, es, E);
  edge_agg_kernel<<<(N + 3) / 4, 256, 0, stream>>>(Kb, QV, Sb, cnt, es, Hb, N);

  // ---- layer 2 ----
  gemm_mfma_kernel<<<gemmBlocks, 256, 0, stream>>>(
      nullptr, Hb, 0, WT + 65536, bcat + 512, Kb, QV, Sb, N, gemmBlocks,
      nullptr, nullptr, nullptr, nullptr, 0);
  edge_agg_kernel<<<(N + 3) / 4, 256, 0, stream>>>(Kb, QV, Sb, cnt, es, Hb, N);

  // ---- pool + fc ----
  pool_sum_kernel<<<1024, 256, 0, stream>>>(Hb, batch, partial, N);
  fc_kernel<<<64, 128, 0, stream>>>(partial, batch, fcW, fcb, out, N);
}

// Round 12
// 351.639 us; speedup vs baseline: 1.0416x; 1.0416x over previous
//
#include <hip/hip_runtime.h>
#include <math.h>

// ---------------------------------------------------------------------------
// ResGatedGraphConv x2 + global_mean_pool + FC.
// R2: bf16 MFMA GEMMs. R4: rcp/exp2 sigmoid. R8: QV interleave, no pool
//     atomics. R9: direct-slot CSR, gemm1 stages fp32 X, S bf16.
// R10: edge_agg 2 edges per slot-iteration (8 gathers in flight).
// R11: UN-fuse scatter from gemm (R10 regression: scatter blocks inherited
//     52KB LDS + 76 VGPR -> 3 blocks/CU -> latency-bound atomics at 1/8
//     concurrency, 100us dispatch). Scatter is its own 4-VGPR kernel again.
//     8 dispatches: prep, scatter, gemm1, edge1, gemm2, edge2, pool, fc.
// ---------------------------------------------------------------------------

typedef __attribute__((ext_vector_type(8))) short short8;
typedef __attribute__((ext_vector_type(4))) float floatx4;
typedef __attribute__((ext_vector_type(8))) unsigned short ushort8v;

#define LOG2E 1.4426950408889634f
#define DSTRIDE 96   // CSR row slots; deg ~ Binom(800k,1/50k): mean16 sd4

__device__ __forceinline__ unsigned short f2b(float f) {
  unsigned int u = __builtin_bit_cast(unsigned int, f);
  u += 0x7fff + ((u >> 16) & 1);   // RNE
  return (unsigned short)(u >> 16);
}
__device__ __forceinline__ float blo(unsigned int u) {
  return __builtin_bit_cast(float, u << 16);
}
__device__ __forceinline__ float bhi(unsigned int u) {
  return __builtin_bit_cast(float, u & 0xffff0000u);
}

// ---------------- direct-slot CSR scatter (lean: 4 VGPR, no LDS) ----------

__global__ __launch_bounds__(256) void scatter_kernel(const int* __restrict__ src,
                                                      const int* __restrict__ dst,
                                                      int* __restrict__ cnt,
                                                      int* __restrict__ es, int E) {
  int e = blockIdx.x * 256 + threadIdx.x;
  if (e < E) {
    int i = dst[e];
    int p = atomicAdd(&cnt[i], 1);
    if (p < DSTRIDE) es[i * DSTRIDE + p] = src[e];
  }
}

// ------- fused prep: zero cnt | pack W bf16 [n][k] | pack biases ----

__global__ __launch_bounds__(256) void prep_kernel(
    const float* __restrict__ Wk1, const float* __restrict__ Wq1,
    const float* __restrict__ Wv1, const float* __restrict__ Ws1,
    const float* __restrict__ Wk2, const float* __restrict__ Wq2,
    const float* __restrict__ Wv2, const float* __restrict__ Ws2,
    unsigned short* __restrict__ WT,
    const float* __restrict__ bk1, const float* __restrict__ bq1,
    const float* __restrict__ bv1, const float* __restrict__ bs1,
    const float* __restrict__ b1,
    const float* __restrict__ bk2, const float* __restrict__ bq2,
    const float* __restrict__ bv2, const float* __restrict__ bs2,
    const float* __restrict__ b2,
    float* __restrict__ bcat,
    int* __restrict__ cnt, int ncnt4, int nzerob) {
  int b = blockIdx.x;
  if (b < nzerob) {
    int i = b * 256 + threadIdx.x;
    if (i < ncnt4) ((int4*)cnt)[i] = make_int4(0, 0, 0, 0);
    return;
  }
  b -= nzerob;
  if (b < 512) {
    int idx = b * 256 + threadIdx.x;   // 0 .. 131071
    int layer = idx >> 16;
    int rem = idx & 0xFFFF;
    int mat = rem >> 14;
    int nk = rem & 0x3FFF;
    int nn = nk >> 7, kk = nk & 127;
    int sel = layer * 4 + mat;
    const float* W = (sel == 0) ? Wk1 : (sel == 1) ? Wq1 : (sel == 2) ? Wv1 :
                     (sel == 3) ? Ws1 : (sel == 4) ? Wk2 : (sel == 5) ? Wq2 :
                     (sel == 6) ? Wv2 : Ws2;
    WT[idx] = f2b(W[kk * 128 + nn]);
    return;
  }
  b -= 512;
  {
    int idx = b * 256 + threadIdx.x;   // 0 .. 1023
    if (idx >= 1024) return;
    int layer = idx >> 9;
    int rem = idx & 511;
    int mat = rem >> 7, c = rem & 127;
    int sel = layer * 4 + mat;
    const float* bb = (sel == 0) ? bk1 : (sel == 1) ? bq1 : (sel == 2) ? bv1 :
                      (sel == 3) ? bs1 : (sel == 4) ? bk2 : (sel == 5) ? bq2 :
                      (sel == 6) ? bv2 : bs2;
    float v = bb[c];
    if (mat == 3) v += (layer == 0) ? b1[c] : b2[c];
    bcat[idx] = v;
  }
}

// --- MFMA GEMM: one staged A-tile serves 2 matrices (blockIdx.y in {0,1}) ---
// Input: fp32 Xf (layer 1) or bf16 Xb (layer 2). Outputs bf16:
// m0 -> Kb[n][128]; m1 -> QV[n][0..127]; m2 -> QV[n][128..255]; m3 -> Sb.

__global__ __launch_bounds__(256) void gemm_mfma_kernel(
    const float* __restrict__ Xf, const unsigned short* __restrict__ Xb,
    int use_fp32,
    const unsigned short* __restrict__ WT,   // [4][128 n][128 k] bf16
    const float* __restrict__ bcat,          // [4][128]
    unsigned short* __restrict__ Kb, unsigned short* __restrict__ QV,
    unsigned short* __restrict__ Sb, int n) {
  __shared__ unsigned short aT[128 * 136];     // 34.8 KB
  __shared__ float estage_all[4][16 * 68];     // 17.4 KB, per-wave strips

  int t = threadIdx.x;
  int row0 = blockIdx.x * 128;
  int ysel = blockIdx.y;

  if (use_fp32) {
#pragma unroll
    for (int i = 0; i < 8; ++i) {
      int c = i * 256 + t;          // 8-ch chunk id, 0..2047
      int r = c >> 4, col16 = c & 15;
      ushort8v o;
#pragma unroll
      for (int q = 0; q < 8; ++q) o[q] = 0;
      if (row0 + r < n) {
        float4 u0 = *(const float4*)&Xf[(size_t)(row0 + r) * 128 + col16 * 8];
        float4 u1 = *(const float4*)&Xf[(size_t)(row0 + r) * 128 + col16 * 8 + 4];
        o[0] = f2b(u0.x); o[1] = f2b(u0.y); o[2] = f2b(u0.z); o[3] = f2b(u0.w);
        o[4] = f2b(u1.x); o[5] = f2b(u1.y); o[6] = f2b(u1.z); o[7] = f2b(u1.w);
      }
      *(ushort8v*)&aT[r * 136 + col16 * 8] = o;
    }
  } else {
#pragma unroll
    for (int i = 0; i < 8; ++i) {
      int c = i * 256 + t;
      int r = c >> 4, col16 = c & 15;
      int4 v = make_int4(0, 0, 0, 0);
      if (row0 + r < n) v = *(const int4*)&Xb[(size_t)(row0 + r) * 128 + col16 * 8];
      *(int4*)&aT[r * 136 + col16 * 8] = v;
    }
  }
  __syncthreads();

  int lane = t & 63, wid = t >> 6;
  int wy = wid >> 1, wx = wid & 1;
  int l15 = lane & 15, lq = lane >> 4;
  int r4 = lane >> 2, cq4 = lane & 3;
  int col = wx * 64 + cq4 * 16;
  float* estage = estage_all[wid];

#pragma unroll
  for (int mm = 0; mm < 2; ++mm) {
    int m = ysel * 2 + mm;
    const unsigned short* WTm = WT + (size_t)m * 16384;

    floatx4 acc[4][4];
#pragma unroll
    for (int mf = 0; mf < 4; ++mf)
#pragma unroll
      for (int nf = 0; nf < 4; ++nf) acc[mf][nf] = (floatx4)(0.0f);

#pragma unroll
    for (int ks = 0; ks < 4; ++ks) {
      int kof = ks * 32 + lq * 8;
      short8 a[4], b[4];
#pragma unroll
      for (int mf = 0; mf < 4; ++mf)
        a[mf] = *(const short8*)&aT[(wy * 64 + mf * 16 + l15) * 136 + kof];
#pragma unroll
      for (int nf = 0; nf < 4; ++nf)
        b[nf] = *(const short8*)&WTm[(size_t)(wx * 64 + nf * 16 + l15) * 128 + kof];
#pragma unroll
      for (int mf = 0; mf < 4; ++mf)
#pragma unroll
        for (int nf = 0; nf < 4; ++nf)
          acc[mf][nf] = __builtin_amdgcn_mfma_f32_16x16x32_bf16(a[mf], b[nf], acc[mf][nf], 0, 0, 0);
    }

    const float* bias = bcat + m * 128;
    float4 bv[4];
#pragma unroll
    for (int j = 0; j < 4; ++j) bv[j] = *(const float4*)&bias[col + j * 4];

    unsigned short* Ob;
    int ostr;
    if (m == 0)      { Ob = Kb;       ostr = 128; }
    else if (m == 1) { Ob = QV;       ostr = 256; }
    else if (m == 2) { Ob = QV + 128; ostr = 256; }
    else             { Ob = Sb;       ostr = 128; }

#pragma unroll
    for (int mf = 0; mf < 4; ++mf) {
#pragma unroll
      for (int nf = 0; nf < 4; ++nf)
#pragma unroll
        for (int i = 0; i < 4; ++i)
          estage[(lq * 4 + i) * 68 + nf * 16 + l15] = acc[mf][nf][i];
      // per-wave region, wave-lockstep: no barrier needed
      int grow = row0 + wy * 64 + mf * 16 + r4;
      if (grow < n) {
        float4 p[4];
#pragma unroll
        for (int j = 0; j < 4; ++j) {
          float4 e = *(const float4*)&estage[r4 * 68 + cq4 * 16 + j * 4];
          p[j].x = e.x + bv[j].x; p[j].y = e.y + bv[j].y;
          p[j].z = e.z + bv[j].z; p[j].w = e.w + bv[j].w;
        }
        ushort8v o0, o1;
        o0[0] = f2b(p[0].x); o0[1] = f2b(p[0].y); o0[2] = f2b(p[0].z); o0[3] = f2b(p[0].w);
        o0[4] = f2b(p[1].x); o0[5] = f2b(p[1].y); o0[6] = f2b(p[1].z); o0[7] = f2b(p[1].w);
        o1[0] = f2b(p[2].x); o1[1] = f2b(p[2].y); o1[2] = f2b(p[2].z); o1[3] = f2b(p[2].w);
        o1[4] = f2b(p[3].x); o1[5] = f2b(p[3].y); o1[6] = f2b(p[3].z); o1[7] = f2b(p[3].w);
        *(ushort8v*)&Ob[(size_t)grow * ostr + col] = o0;
        *(ushort8v*)&Ob[(size_t)grow * ostr + col + 8] = o1;
      }
    }
  }
}

// ---------------- edge aggregation + residual + relu ----------------
// h[i] = relu( S[i] + sum_j sigmoid(K[i]+Q[j]) * V[j] )
// One node per wave; 4 edge slots x 16 lanes x 8 ch; TWO edges per slot
// iteration (8 gathers in flight per wave); all loads loop-local (no spill).

__global__ __launch_bounds__(256) void edge_agg_kernel(
    const unsigned short* __restrict__ Kb, const unsigned short* __restrict__ QV,
    const unsigned short* __restrict__ Sb, const int* __restrict__ cnt,
    const int* __restrict__ es, unsigned short* __restrict__ Hb, int n) {
  int wid = threadIdx.x >> 6;
  int lane = threadIdx.x & 63;
  int node = blockIdx.x * 4 + wid;
  if (node >= n) return;
  int slot = lane >> 4;      // edge slot 0..3
  int l16 = lane & 15;       // channels l16*8 .. l16*8+7
  int chb = l16 * 8;

  uint4 kk = *(const uint4*)&Kb[(size_t)node * 128 + chb];
  float kc0 = blo(kk.x) * (-LOG2E), kc1 = bhi(kk.x) * (-LOG2E);
  float kc2 = blo(kk.y) * (-LOG2E), kc3 = bhi(kk.y) * (-LOG2E);
  float kc4 = blo(kk.z) * (-LOG2E), kc5 = bhi(kk.z) * (-LOG2E);
  float kc6 = blo(kk.w) * (-LOG2E), kc7 = bhi(kk.w) * (-LOG2E);

  float a0 = 0.f, a1 = 0.f, a2 = 0.f, a3 = 0.f;
  float a4 = 0.f, a5 = 0.f, a6 = 0.f, a7 = 0.f;

  int count = cnt[node];
  if (count > DSTRIDE) count = DSTRIDE;
  const int* row = es + (size_t)node * DSTRIDE;
  int e = slot;
  while (e + 4 < count) {
    int j0 = row[e];
    int j1 = row[e + 4];
    const unsigned short* qv0 = &QV[(size_t)j0 * 256 + chb];
    const unsigned short* qv1 = &QV[(size_t)j1 * 256 + chb];
    uint4 q8 = *(const uint4*)qv0;
    uint4 v8 = *(const uint4*)(qv0 + 128);
    uint4 q9 = *(const uint4*)qv1;
    uint4 v9 = *(const uint4*)(qv1 + 128);
    float ex;
    ex = __builtin_amdgcn_exp2f(fmaf(blo(q8.x), -LOG2E, kc0));
    a0 = fmaf(blo(v8.x), __builtin_amdgcn_rcpf(1.0f + ex), a0);
    ex = __builtin_amdgcn_exp2f(fmaf(bhi(q8.x), -LOG2E, kc1));
    a1 = fmaf(bhi(v8.x), __builtin_amdgcn_rcpf(1.0f + ex), a1);
    ex = __builtin_amdgcn_exp2f(fmaf(blo(q8.y), -LOG2E, kc2));
    a2 = fmaf(blo(v8.y), __builtin_amdgcn_rcpf(1.0f + ex), a2);
    ex = __builtin_amdgcn_exp2f(fmaf(bhi(q8.y), -LOG2E, kc3));
    a3 = fmaf(bhi(v8.y), __builtin_amdgcn_rcpf(1.0f + ex), a3);
    ex = __builtin_amdgcn_exp2f(fmaf(blo(q8.z), -LOG2E, kc4));
    a4 = fmaf(blo(v8.z), __builtin_amdgcn_rcpf(1.0f + ex), a4);
    ex = __builtin_amdgcn_exp2f(fmaf(bhi(q8.z), -LOG2E, kc5));
    a5 = fmaf(bhi(v8.z), __builtin_amdgcn_rcpf(1.0f + ex), a5);
    ex = __builtin_amdgcn_exp2f(fmaf(blo(q8.w), -LOG2E, kc6));
    a6 = fmaf(blo(v8.w), __builtin_amdgcn_rcpf(1.0f + ex), a6);
    ex = __builtin_amdgcn_exp2f(fmaf(bhi(q8.w), -LOG2E, kc7));
    a7 = fmaf(bhi(v8.w), __builtin_amdgcn_rcpf(1.0f + ex), a7);
    ex = __builtin_amdgcn_exp2f(fmaf(blo(q9.x), -LOG2E, kc0));
    a0 = fmaf(blo(v9.x), __builtin_amdgcn_rcpf(1.0f + ex), a0);
    ex = __builtin_amdgcn_exp2f(fmaf(bhi(q9.x), -LOG2E, kc1));
    a1 = fmaf(bhi(v9.x), __builtin_amdgcn_rcpf(1.0f + ex), a1);
    ex = __builtin_amdgcn_exp2f(fmaf(blo(q9.y), -LOG2E, kc2));
    a2 = fmaf(blo(v9.y), __builtin_amdgcn_rcpf(1.0f + ex), a2);
    ex = __builtin_amdgcn_exp2f(fmaf(bhi(q9.y), -LOG2E, kc3));
    a3 = fmaf(bhi(v9.y), __builtin_amdgcn_rcpf(1.0f + ex), a3);
    ex = __builtin_amdgcn_exp2f(fmaf(blo(q9.z), -LOG2E, kc4));
    a4 = fmaf(blo(v9.z), __builtin_amdgcn_rcpf(1.0f + ex), a4);
    ex = __builtin_amdgcn_exp2f(fmaf(bhi(q9.z), -LOG2E, kc5));
    a5 = fmaf(bhi(v9.z), __builtin_amdgcn_rcpf(1.0f + ex), a5);
    ex = __builtin_amdgcn_exp2f(fmaf(blo(q9.w), -LOG2E, kc6));
    a6 = fmaf(blo(v9.w), __builtin_amdgcn_rcpf(1.0f + ex), a6);
    ex = __builtin_amdgcn_exp2f(fmaf(bhi(q9.w), -LOG2E, kc7));
    a7 = fmaf(bhi(v9.w), __builtin_amdgcn_rcpf(1.0f + ex), a7);
    e += 8;
  }
  if (e < count) {
    int j0 = row[e];
    const unsigned short* qv0 = &QV[(size_t)j0 * 256 + chb];
    uint4 q8 = *(const uint4*)qv0;
    uint4 v8 = *(const uint4*)(qv0 + 128);
    float ex;
    ex = __builtin_amdgcn_exp2f(fmaf(blo(q8.x), -LOG2E, kc0));
    a0 = fmaf(blo(v8.x), __builtin_amdgcn_rcpf(1.0f + ex), a0);
    ex = __builtin_amdgcn_exp2f(fmaf(bhi(q8.x), -LOG2E, kc1));
    a1 = fmaf(bhi(v8.x), __builtin_amdgcn_rcpf(1.0f + ex), a1);
    ex = __builtin_amdgcn_exp2f(fmaf(blo(q8.y), -LOG2E, kc2));
    a2 = fmaf(blo(v8.y), __builtin_amdgcn_rcpf(1.0f + ex), a2);
    ex = __builtin_amdgcn_exp2f(fmaf(bhi(q8.y), -LOG2E, kc3));
    a3 = fmaf(bhi(v8.y), __builtin_amdgcn_rcpf(1.0f + ex), a3);
    ex = __builtin_amdgcn_exp2f(fmaf(blo(q8.z), -LOG2E, kc4));
    a4 = fmaf(blo(v8.z), __builtin_amdgcn_rcpf(1.0f + ex), a4);
    ex = __builtin_amdgcn_exp2f(fmaf(bhi(q8.z), -LOG2E, kc5));
    a5 = fmaf(bhi(v8.z), __builtin_amdgcn_rcpf(1.0f + ex), a5);
    ex = __builtin_amdgcn_exp2f(fmaf(blo(q8.w), -LOG2E, kc6));
    a6 = fmaf(blo(v8.w), __builtin_amdgcn_rcpf(1.0f + ex), a6);
    ex = __builtin_amdgcn_exp2f(fmaf(bhi(q8.w), -LOG2E, kc7));
    a7 = fmaf(bhi(v8.w), __builtin_amdgcn_rcpf(1.0f + ex), a7);
  }

  // combine 4 edge slots
  a0 += __shfl_xor(a0, 16); a0 += __shfl_xor(a0, 32);
  a1 += __shfl_xor(a1, 16); a1 += __shfl_xor(a1, 32);
  a2 += __shfl_xor(a2, 16); a2 += __shfl_xor(a2, 32);
  a3 += __shfl_xor(a3, 16); a3 += __shfl_xor(a3, 32);
  a4 += __shfl_xor(a4, 16); a4 += __shfl_xor(a4, 32);
  a5 += __shfl_xor(a5, 16); a5 += __shfl_xor(a5, 32);
  a6 += __shfl_xor(a6, 16); a6 += __shfl_xor(a6, 32);
  a7 += __shfl_xor(a7, 16); a7 += __shfl_xor(a7, 32);

  if (slot == 0) {
    uint4 sb = *(const uint4*)&Sb[(size_t)node * 128 + chb];
    float r0 = fmaxf(a0 + blo(sb.x), 0.f), r1 = fmaxf(a1 + bhi(sb.x), 0.f);
    float r2 = fmaxf(a2 + blo(sb.y), 0.f), r3 = fmaxf(a3 + bhi(sb.y), 0.f);
    float r4 = fmaxf(a4 + blo(sb.z), 0.f), r5 = fmaxf(a5 + bhi(sb.z), 0.f);
    float r6 = fmaxf(a6 + blo(sb.w), 0.f), r7 = fmaxf(a7 + bhi(sb.w), 0.f);
    ushort8v o;
    o[0] = f2b(r0); o[1] = f2b(r1); o[2] = f2b(r2); o[3] = f2b(r3);
    o[4] = f2b(r4); o[5] = f2b(r5); o[6] = f2b(r6); o[7] = f2b(r7);
    *(ushort8v*)&Hb[(size_t)node * 128 + chb] = o;
  }
}

// ---------------- mean pool + FC (graph bounds via binary search) ----------

__device__ __forceinline__ int lb_batch(const int* __restrict__ batch, int n, int key) {
  int lo = 0, hi = n;
  while (lo < hi) {
    int mid = (lo + hi) >> 1;
    if (batch[mid] < key) lo = mid + 1; else hi = mid;
  }
  return lo;
}

// 16 slices per graph -> partial[slice][g][128], no atomics.
__global__ __launch_bounds__(256) void pool_sum_kernel(const unsigned short* __restrict__ Hb,
                                                       const int* __restrict__ batch,
                                                       float* __restrict__ partial, int n) {
  __shared__ float red[8 * 128];
  int g = blockIdx.x >> 4;
  int slice = blockIdx.x & 15;
  int t = threadIdx.x;
  int grp = t >> 5;        // 0..7: node stripe
  int cq = t & 31;         // channel quad: ch cq*4..cq*4+3
  int s = lb_batch(batch, n, g), e = lb_batch(batch, n, g + 1);
  int cntn = e - s;
  int per = (cntn + 15) >> 4;
  int ss = s + slice * per;
  int ee = ss + per; if (ee > e) ee = e;

  float4 acc = make_float4(0.f, 0.f, 0.f, 0.f);
  for (int nd = ss + grp; nd < ee; nd += 8) {
    uint2 u = *(const uint2*)&Hb[(size_t)nd * 128 + cq * 4];
    acc.x += blo(u.x); acc.y += bhi(u.x);
    acc.z += blo(u.y); acc.w += bhi(u.y);
  }
  *(float4*)&red[grp * 128 + cq * 4] = acc;
  __syncthreads();
  if (t < 128) {
    float tot = 0.f;
#pragma unroll
    for (int g8 = 0; g8 < 8; ++g8) tot += red[g8 * 128 + t];
    partial[(size_t)slice * 8192 + g * 128 + t] = tot;
  }
}

__global__ __launch_bounds__(128) void fc_kernel(const float* __restrict__ partial,
                                                 const int* __restrict__ batch,
                                                 const float* __restrict__ fcW,
                                                 const float* __restrict__ fcb,
                                                 float* __restrict__ out, int n) {
  __shared__ float p[128];
  int g = blockIdx.x;
  int t = threadIdx.x;
  int cntn = lb_batch(batch, n, g + 1) - lb_batch(batch, n, g);
  float inv = 1.0f / (float)((cntn > 0) ? cntn : 1);
  float tot = 0.f;
#pragma unroll
  for (int s = 0; s < 16; ++s) tot += partial[(size_t)s * 8192 + g * 128 + t];
  p[t] = tot * inv;
  __syncthreads();
  if (t < 10) {
    float s = fcb[t];
    for (int c = 0; c < 128; ++c) s += p[c] * fcW[c * 10 + t];
    out[g * 10 + t] = s;
  }
}

// ---------------------------------------------------------------------------

extern "C" void kernel_launch(void* const* d_in, const int* in_sizes, int n_in,
                              void* d_out, int out_size, void* d_ws, size_t ws_size,
                              hipStream_t stream) {
  const float* x   = (const float*)d_in[0];
  const int* eidx  = (const int*)d_in[1];
  const int* batch = (const int*)d_in[2];
  const float* Wk1 = (const float*)d_in[3];  const float* bk1 = (const float*)d_in[4];
  const float* Wq1 = (const float*)d_in[5];  const float* bq1 = (const float*)d_in[6];
  const float* Wv1 = (const float*)d_in[7];  const float* bv1 = (const float*)d_in[8];
  const float* Ws1 = (const float*)d_in[9];  const float* bs1 = (const float*)d_in[10];
  const float* b1  = (const float*)d_in[11];
  const float* Wk2 = (const float*)d_in[12]; const float* bk2 = (const float*)d_in[13];
  const float* Wq2 = (const float*)d_in[14]; const float* bq2 = (const float*)d_in[15];
  const float* Wv2 = (const float*)d_in[16]; const float* bv2 = (const float*)d_in[17];
  const float* Ws2 = (const float*)d_in[18]; const float* bs2 = (const float*)d_in[19];
  const float* b2  = (const float*)d_in[20];
  const float* fcW = (const float*)d_in[21]; const float* fcb = (const float*)d_in[22];
  float* out = (float*)d_out;

  const int N = in_sizes[0] / 128;   // 50000
  const int E = in_sizes[1] / 2;     // 800000
  const int* src = eidx;
  const int* dst = eidx + E;

  // ---- workspace carve ----
  char* w = (char*)d_ws;
  size_t off = 0;
  auto carve = [&](size_t bytes) -> void* {
    void* p = w + off;
    off += (bytes + 255) & ~size_t(255);
    return p;
  };
  const size_t featB16 = (size_t)N * 128 * 2;
  unsigned short* Kb = (unsigned short*)carve(featB16);
  unsigned short* QV = (unsigned short*)carve(featB16 * 2);  // [n][256] Q|V
  unsigned short* Hb = (unsigned short*)carve(featB16);
  unsigned short* Sb = (unsigned short*)carve(featB16);
  unsigned short* WT = (unsigned short*)carve(2 * 4 * 128 * 128 * 2);
  float* bcat = (float*)carve(1024 * 4);
  int* cnt     = (int*)carve(((size_t)N + 4) * 4);
  int* es      = (int*)carve((size_t)N * DSTRIDE * 4);
  float* partial = (float*)carve((size_t)16 * 64 * 128 * 4);
  (void)ws_size; (void)n_in; (void)out_size;

  // ---- prep (zero cnt, pack weights/biases), then lean scatter ----
  int ncnt4 = (N + 3) / 4;
  int nzerob = (ncnt4 + 255) / 256;
  prep_kernel<<<nzerob + 512 + 4, 256, 0, stream>>>(
      Wk1, Wq1, Wv1, Ws1, Wk2, Wq2, Wv2, Ws2, WT,
      bk1, bq1, bv1, bs1, b1, bk2, bq2, bv2, bs2, b2, bcat,
      cnt, ncnt4, nzerob);

  scatter_kernel<<<(E + 255) / 256, 256, 0, stream>>>(src, dst, cnt, es, E);

  dim3 ggrid((N + 127) / 128, 2);

  // ---- layer 1 (stages fp32 x directly) ----
  gemm_mfma_kernel<<<ggrid, 256, 0, stream>>>(x, nullptr, 1, WT, bcat,
                                              Kb, QV, Sb, N);
  edge_agg_kernel<<<(N + 3) / 4, 256, 0, stream>>>(Kb, QV, Sb, cnt, es, Hb, N);

  // ---- layer 2 ----
  gemm_mfma_kernel<<<ggrid, 256, 0, stream>>>(nullptr, Hb, 0, WT + 65536,
                                              bcat + 512, Kb, QV, Sb, N);
  edge_agg_kernel<<<(N + 3) / 4, 256, 0, stream>>>(Kb, QV, Sb, cnt, es, Hb, N);

  // ---- pool + fc ----
  pool_sum_kernel<<<1024, 256, 0, stream>>>(Hb, batch, partial, N);
  fc_kernel<<<64, 128, 0, stream>>>(partial, batch, fcW, fcb, out, N);
}